// Round 11
// baseline (5131.914 us; speedup 1.0000x reference)
//
#include <hip/hip_runtime.h>

typedef _Float16 f16x8 __attribute__((ext_vector_type(8)));
typedef float    f32x4 __attribute__((ext_vector_type(4)));
typedef unsigned long long u64;
typedef u64 u64x2 __attribute__((ext_vector_type(2)));

constexpr int BATCH = 1024;
constexpr int HDIM  = 512;
constexpr int TENC  = 512;
constexpr int PRED  = 48;
constexpr int STEPS = TENC + PRED - 1;   // 559 cell steps; loop runs 560 (last = fc only)
constexpr int GB    = 16;                // batches per group = one MFMA m-tile
constexpr int UBU   = 64;                // units per block (4 waves x 16)
constexpr int GPB   = 4;                 // groups per block: 4-phase pipeline
constexpr int NCL   = 16;                // clusters of 8 blocks
constexpr int HB_OFF = 32768;

// R21 = R20's 4-group pipeline + register-liveness discipline. R17/R20
// aborted (not hung): their DUMMY x-loads produced dead asm-load defs; the
// compiler frees an inline-asm output's VGPR at the asm statement (it has
// no model of the latent write), reallocates it, and the in-flight load
// return clobbers live data (store addresses!) -> memory fault. Fix:
// (a) no dummy loads -- decode/STEPS epilogues load REAL x (col TENC-1,
//     value unused) into the live xpre registers, keeping 9 ops/phase;
// (b) after every boundary wait, an empty asm USE of xcur[0..3] pins each
//     x-def to a post-wait use so its VGPR is live (unrecyclable) while
//     the load is in flight. tcur defs are consumed by the tag check.
// Everything else = R20: fenced waits (rule #18), steady vmcnt(10) ledger
// (9 vmem ops/phase: 4h+4x then 1 store; edges t=0 -> 8/9/10/10,
// t=STEPS -> 10/9/8/0), in-band tags (ABA-safe at D=4: storing h_g(t+2)
// requires all peers stored h_g(t+1), which requires the slowest peer to
// have finished validating h_g(t) -- no overwrite-under-reader), preds
// buffered in LDS, raw lds_barrier (no vmcnt drain).
constexpr u64 TAG_MASK = 0x0001000100010001ull;
__device__ __forceinline__ u64 tag_of(int t) {
  return ((u64)(t & 1) | ((u64)((t >> 1) & 1) << 16)) * 0x0000000100000001ull;
}

__global__ void init_kernel(int* wsi) {
  int idx = blockIdx.x * blockDim.x + threadIdx.x;
  int stride = gridDim.x * blockDim.x;
  const int nws = (HB_OFF + BATCH * HDIM * 2) / 4;  // hbuf[0] = h_0 = 0 (tag 00)
  for (int i = idx; i < nws; i += stride) wsi[i] = 0;
  // hbuf[1] stays poison -> tag-invalid until written
}

static __device__ __forceinline__ f16x8 load16_llc(const _Float16* p) {
  f16x8 v;
  asm volatile("global_load_dwordx4 %0, %1, off sc0 sc1"
               : "=v"(v) : "v"((u64)p) : "memory");
  return v;
}
static __device__ __forceinline__ unsigned loadc_llc(const void* p) {
  unsigned v;   // 4B canary: in-band tag probe
  asm volatile("global_load_dword %0, %1, off sc0 sc1"
               : "=v"(v) : "v"((u64)p) : "memory");
  return v;
}
static __device__ __forceinline__ float loadx(const float* p) {
  float v;   // plain cached load via asm so compiler never drains our pipeline
  asm volatile("global_load_dword %0, %1, off"
               : "=v"(v) : "v"((u64)p) : "memory");
  return v;
}
// s_sleep needs a literal operand: 4-step constant backoff ladder.
static __device__ __forceinline__ void sleep_bk(int stage) {
  if (stage == 0)      __builtin_amdgcn_s_sleep(1);
  else if (stage == 1) __builtin_amdgcn_s_sleep(2);
  else if (stage == 2) __builtin_amdgcn_s_sleep(4);
  else                 __builtin_amdgcn_s_sleep(8);
}
// fenced waits (rule #18): checks gating on a wait must not hoist above it.
static __device__ __forceinline__ void wait_vm0_fenced() {
  asm volatile("s_waitcnt vmcnt(0)" ::: "memory");
  __builtin_amdgcn_sched_barrier(0);
}
static __device__ __forceinline__ void wait_vm8_fenced() {
  asm volatile("s_waitcnt vmcnt(8)" ::: "memory");
  __builtin_amdgcn_sched_barrier(0);
}
static __device__ __forceinline__ void wait_vm9_fenced() {
  asm volatile("s_waitcnt vmcnt(9)" ::: "memory");
  __builtin_amdgcn_sched_barrier(0);
}
static __device__ __forceinline__ void wait_vm10_fenced() {
  asm volatile("s_waitcnt vmcnt(10)" ::: "memory");
  __builtin_amdgcn_sched_barrier(0);
}
// raw barrier: LDS-drain + s_barrier, NO vmcnt drain (stores/loads in flight)
static __device__ __forceinline__ void lds_barrier() {
  asm volatile("s_waitcnt lgkmcnt(0)" ::: "memory");
  __builtin_amdgcn_s_barrier();
}

__global__ __launch_bounds__(256, 1) void lstm_persist(
    const float* __restrict__ x,
    const float* __restrict__ w_ih,
    const float* __restrict__ w_hh,
    const float* __restrict__ b_ih,
    const float* __restrict__ b_hh,
    const float* __restrict__ w_fc,
    const float* __restrict__ b_fc,
    float* __restrict__ out,          // [1024][48] fp32
    _Float16* __restrict__ hbuf)      // [2][1024][512] fp16 ping-pong, tagged
{
  const int bid  = blockIdx.x;        // 128 blocks: 16 clusters x 8 unit-slices
  const int cl   = bid >> 3;
  const int ub   = bid & 7;
  const int tid  = threadIdx.x;
  const int wid  = tid >> 6;
  const int lane = tid & 63;
  const int quad = lane >> 4;
  const int lcol = lane & 15;
  const int myu  = ub * UBU + wid * 16 + lcol;

  __shared__ __align__(16) _Float16 hsA[GB][520];    // 16.6 KB
  __shared__ __align__(16) _Float16 hsB[GB][520];    // 16.6 KB
  __shared__ __align__(16) _Float16 wz[520];         // fp16 w_fc + zero pad
  __shared__ __align__(16) _Float16 rp[GB][UBU];     // 2 KB h-store repack
  __shared__ float outs[GPB][GB][PRED];              // 12 KB predictions

  for (int k = tid; k < 512; k += 256) wz[k] = (_Float16)w_fc[k];
  if (tid < 8) wz[512 + tid] = (_Float16)0.f;

  // ---- full-K weight B-frags (n=lcol, k=kc*32+quad*8+j) ----
  f16x8 wf[4][16];
  float wih[4], bias[4];
#pragma unroll
  for (int nt = 0; nt < 4; ++nt) {
    const int j = nt * HDIM + myu;
    wih[nt]  = w_ih[j];
    bias[nt] = b_ih[j] + b_hh[j];
#pragma unroll
    for (int kc = 0; kc < 16; ++kc) {
      const float* s = w_hh + (size_t)j * HDIM + kc * 32 + quad * 8;
      f16x8 v;
#pragma unroll
      for (int i = 0; i < 8; ++i) v[i] = (_Float16)s[i];
      wf[nt][kc] = v;
    }
  }
  const float bfc = b_fc[0];

  float cst[GPB][4];
#pragma unroll
  for (int g = 0; g < GPB; ++g)
#pragma unroll
    for (int r = 0; r < 4; ++r) cst[g][r] = 0.f;

  // prefetch register sets, shared by disjoint-lifetime pairs (0,2) / (1,3)
  f16x8 tXa[4], tXb[4];
  float xva[4], xvb[4];

  auto issue4 = [&](f16x8* tr, const _Float16* base) {
#pragma unroll
    for (int i = 0; i < 4; ++i) {
      const int c = i * 256 + tid;
      tr[i] = load16_llc(base + (size_t)(c >> 6) * HDIM + (c & 63) * 8);
    }
  };
  // canary validate (R15/R18-proven): stale path polls 4B/chunk with sleep
  // ladder; 16B reload once canary flips; re-check clears chunk. All checks
  // fenced behind their waits; all load defs consumed after covering waits.
  auto validate4 = [&](f16x8* tr, const _Float16* base, u64 expect) {
    const unsigned exp32 = (unsigned)expect & 0x00010001u;
    unsigned stale = 0;
#pragma unroll
    for (int i = 0; i < 4; ++i) {
      u64x2 w2 = __builtin_bit_cast(u64x2, tr[i]);
      if (((w2[0] & TAG_MASK) != expect) || ((w2[1] & TAG_MASK) != expect))
        stale |= 1u << i;
    }
    int slp = 0;
    while (stale) {
      sleep_bk(slp);
      if (slp < 3) ++slp;
      unsigned cv[4];
#pragma unroll
      for (int i = 0; i < 4; ++i)
        if (stale & (1u << i)) {
          const int c = i * 256 + tid;
          cv[i] = loadc_llc(base + (size_t)(c >> 6) * HDIM + (c & 63) * 8);
        }
      wait_vm0_fenced();          // canary values readable only after this
      unsigned rdy = 0;
#pragma unroll
      for (int i = 0; i < 4; ++i)
        if ((stale & (1u << i)) && ((cv[i] & 0x00010001u) == exp32))
          rdy |= 1u << i;
      if (!rdy) continue;
#pragma unroll
      for (int i = 0; i < 4; ++i)
        if (rdy & (1u << i)) {
          const int c = i * 256 + tid;
          tr[i] = load16_llc(base + (size_t)(c >> 6) * HDIM + (c & 63) * 8);
        }
      wait_vm0_fenced();          // reloads readable only after this
#pragma unroll
      for (int i = 0; i < 4; ++i)
        if (rdy & (1u << i)) {
          u64x2 w2 = __builtin_bit_cast(u64x2, tr[i]);
          if (((w2[0] & TAG_MASK) == expect) && ((w2[1] & TAG_MASK) == expect))
            stale &= ~(1u << i);
        }
    }
  };
  auto stage4 = [&](f16x8* tr, _Float16 (*hsp)[520]) {
#pragma unroll
    for (int i = 0; i < 4; ++i) {
      const int c = i * 256 + tid;
      *reinterpret_cast<f16x8*>(&hsp[c >> 6][(c & 63) * 8]) = tr[i];
    }
  };
  auto gemm = [&](const _Float16 (*hsp)[520], f32x4* acc, f32x4& accF, bool dec) {
#pragma unroll
    for (int kc = 0; kc < 16; ++kc) {
      const f16x8 a = *reinterpret_cast<const f16x8*>(&hsp[lcol][kc * 32 + quad * 8]);
#pragma unroll
      for (int nt = 0; nt < 4; ++nt)
        acc[nt] = __builtin_amdgcn_mfma_f32_16x16x32_f16(a, wf[nt][kc], acc[nt], 0, 0, 0);
      if (dec) {   // fc: B row 0 = w_fc, rows 1..15 = 0 (zero-pad broadcast)
        const f16x8 wv = *reinterpret_cast<const f16x8*>(
            &wz[(lcol == 0) ? (kc * 32 + quad * 8) : 512]);
        accF = __builtin_amdgcn_mfma_f32_16x16x32_f16(a, wv, accF, 0, 0, 0);
      }
    }
  };

  lds_barrier();

  // ---- prologue: groups 0,1 step-0 data ([4h,4x] each = 16 ops) ----
  {
    const int b0 = cl * GB;
    issue4(tXa, hbuf + (size_t)b0 * HDIM);
#pragma unroll
    for (int r = 0; r < 4; ++r)
      xva[r] = loadx(x + (size_t)(b0 + quad * 4 + r) * TENC);
    const int b1 = (cl + NCL) * GB;
    issue4(tXb, hbuf + (size_t)b1 * HDIM);
#pragma unroll
    for (int r = 0; r < 4; ++r)
      xvb[r] = loadx(x + (size_t)(b1 + quad * 4 + r) * TENC);
  }

  for (int t = 0; t <= STEPS; ++t) {
    const _Float16* hcur = hbuf + (size_t)(t & 1) * BATCH * HDIM;
    _Float16*       hnxt = hbuf + (size_t)((t + 1) & 1) * BATCH * HDIM;
    const u64 expect = tag_of(t);
    const bool dec = (t >= TENC);

#pragma unroll
    for (int g = 0; g < GPB; ++g) {
      const int bG0 = (cl + NCL * g) * GB;
      f16x8* tcur = (g & 1) ? tXb : tXa;
      float* xcur = (g & 1) ? xvb : xva;
      _Float16 (*hsp)[520] = (g & 1) ? hsB : hsA;

      // boundary wait per the 9-ops/phase ledger (fenced, rule #18)
      if (t == 0) {
        if (g == 0)      wait_vm8_fenced();
        else if (g == 1) wait_vm9_fenced();
        else             wait_vm10_fenced();
      } else if (t == STEPS) {
        if (g == 0)      wait_vm10_fenced();
        else if (g == 1) wait_vm9_fenced();
        else if (g == 2) wait_vm8_fenced();
        else             wait_vm0_fenced();
      } else {
        wait_vm10_fenced();
      }
      // liveness pin: give this group's x-load defs a USE after the wait
      // that covers their landing -- the allocator cannot recycle an
      // in-flight dest VGPR (the R17/R20 fault).
      asm volatile("" :: "v"(xcur[0]), "v"(xcur[1]),
                         "v"(xcur[2]), "v"(xcur[3]));

      validate4(tcur, hcur + (size_t)bG0 * HDIM, expect);
      stage4(tcur, hsp);
      lds_barrier();

      f32x4 acc[4], accF;
#pragma unroll
      for (int nt = 0; nt < 4; ++nt) acc[nt] = (f32x4){0.f, 0.f, 0.f, 0.f};
      accF = (f32x4){0.f, 0.f, 0.f, 0.f};
      gemm(hsp, acc, accF, dec);

      float xcell[4];
      if (dec) {   // xt = fc(h_t); preds buffered in LDS (no vmem op!)
#pragma unroll
        for (int r = 0; r < 4; ++r) xcell[r] = __shfl(accF[r], quad * 16) + bfc;
        if (ub == 0 && wid == 0 && lcol == 0) {
          const int p = t - TENC;
#pragma unroll
          for (int r = 0; r < 4; ++r)
            outs[g][quad * 4 + r][p] = accF[r] + bfc;
        }
      } else {
#pragma unroll
        for (int r = 0; r < 4; ++r) xcell[r] = xcur[r];
      }

      // prefetch target: group g+2 (mod 4); same step for g<2, next for g>=2
      const int gp  = (g + 2) & 3;
      const int bP0 = (cl + NCL * gp) * GB;
      f16x8* tpre = (gp & 1) ? tXb : tXa;
      float* xpre = (gp & 1) ? xvb : xva;

      if (t < STEPS) {
        const u64 tagnew = tag_of(t + 1);
#pragma unroll
        for (int r = 0; r < 4; ++r) {
          const float xt = xcell[r];
          const float gi = acc[0][r] + xt * wih[0] + bias[0];
          const float gf = acc[1][r] + xt * wih[1] + bias[1];
          const float gg = acc[2][r] + xt * wih[2] + bias[2];
          const float go = acc[3][r] + xt * wih[3] + bias[3];
          const float si = 1.f / (1.f + __expf(-gi));
          const float sf = 1.f / (1.f + __expf(-gf));
          const float so = 1.f / (1.f + __expf(-go));
          const float tg = 1.f - 2.f / (1.f + __expf(2.f * gg));
          const float cn = sf * cst[g][r] + si * tg;
          cst[g][r] = cn;
          const float tc = 1.f - 2.f / (1.f + __expf(2.f * cn));
          rp[quad * 4 + r][wid * 16 + lcol] = (_Float16)(so * tc);
        }
        lds_barrier();
        const u64 hv = *reinterpret_cast<const u64*>(&rp[tid >> 4][(tid & 15) * 4]);
        const u64 p4 = (hv & ~TAG_MASK) | tagnew;
        // prefetch loads FIRST so the h-store is the newest vmem op.
        const _Float16* ptgt = (g < 2) ? (hcur + (size_t)bP0 * HDIM)
                                       : (hnxt + (size_t)bP0 * HDIM);
        issue4(tpre, ptgt);
        // ALWAYS real x loads into the live xpre regs (col TENC-1 when past
        // the encoder: value unused, keeps 9-op ledger, no dead defs).
        const int xi = (g < 2) ? t : (t + 1);
        const int xc = (xi < TENC) ? xi : (TENC - 1);
#pragma unroll
        for (int r = 0; r < 4; ++r)
          xpre[r] = loadx(x + (size_t)(bP0 + quad * 4 + r) * TENC + xc);
        _Float16* dst = hnxt + (size_t)(bG0 + (tid >> 4)) * HDIM
                        + ub * UBU + (tid & 15) * 4;
        __hip_atomic_store((u64*)dst, p4, __ATOMIC_RELAXED,
                           __HIP_MEMORY_SCOPE_AGENT);
      } else if (g < 2) {
        // t == STEPS: phases 2,3 still need their same-step prefetch
        issue4(tpre, hcur + (size_t)bP0 * HDIM);
#pragma unroll
        for (int r = 0; r < 4; ++r)
          xpre[r] = loadx(x + (size_t)(bP0 + quad * 4 + r) * TENC + (TENC - 1));
      }
    }
  }

  // flush buffered predictions (all loads drained by t=STEPS g=3's vmcnt(0);
  // their defs were keep-alive'd at the STEPS g=2/g=3 boundaries)
  lds_barrier();
  if (ub == 0) {
    for (int k = tid; k < GPB * GB * PRED; k += 256) {
      const int g  = k / (GB * PRED);
      const int rm = k % (GB * PRED);
      out[(size_t)((cl + NCL * g) * GB + rm / PRED) * PRED + (rm % PRED)] =
          outs[g][rm / PRED][rm % PRED];
    }
  }
}

extern "C" void kernel_launch(void* const* d_in, const int* in_sizes, int n_in,
                              void* d_out, int out_size, void* d_ws, size_t ws_size,
                              hipStream_t stream) {
  const float* x    = (const float*)d_in[0];
  const float* w_ih = (const float*)d_in[1];
  const float* w_hh = (const float*)d_in[2];
  const float* b_ih = (const float*)d_in[3];
  const float* b_hh = (const float*)d_in[4];
  const float* w_fc = (const float*)d_in[5];
  const float* b_fc = (const float*)d_in[6];
  float* out = (float*)d_out;
  _Float16* hbuf = (_Float16*)((char*)d_ws + HB_OFF);

  hipLaunchKernelGGL(init_kernel, dim3(256), dim3(256), 0, stream, (int*)d_ws);
  hipLaunchKernelGGL(lstm_persist, dim3(128), dim3(256), 0, stream,
                     x, w_ih, w_hh, b_ih, b_hh, w_fc, b_fc, out, hbuf);
}

// Round 12
// 2652.267 us; speedup vs baseline: 1.9349x; 1.9349x over previous
//
#include <hip/hip_runtime.h>

typedef _Float16 f16x8 __attribute__((ext_vector_type(8)));
typedef float    f32x4 __attribute__((ext_vector_type(4)));
typedef unsigned long long u64;
typedef u64 u64x2 __attribute__((ext_vector_type(2)));

constexpr int BATCH = 1024;
constexpr int HDIM  = 512;
constexpr int TENC  = 512;
constexpr int PRED  = 48;
constexpr int STEPS = TENC + PRED - 1;   // 559 cell steps; loop runs 560 (last = fc only)
constexpr int NG    = 64;                // groups (16 batches each)
constexpr int GB    = 16;                // batches per group = one MFMA m-tile
constexpr int UBU   = 64;                // units per block (8 waves x 16, 2 gate-sets)
constexpr int HB_OFF = 32768;

// R22: gate-split for occupancy. R21 proved the per-phase cost is a ~2.3us
// FIXED floor (3x prefetch lead bought only 0.5us) -- the stall is exposed
// because ~460 regs/thread (weights wf[4][16]) force 1 wave/SIMD: zero TLP,
// every LDS/vmcnt/barrier latency is serial. Fix: 512-thread blocks, waveset
// 0 (waves 0-3) computes gates i,f; waveset 1 computes g,o -> 128 weight
// regs/thread, total ~230 <= 256 -> __launch_bounds__(512,2) = 2 waves/SIMD.
// Gates cross wavesets via padded LDS gl[4][16][68]; epilogue re-partitioned
// 2 cells/thread (cell-state follows); h-stores 4B/thread (in-band tag per
// dword unchanged); dec fc via xls[16] LDS. Exchange protocol = R18 verbatim
// (tags, canary validate, fenced waits rule #18, vmcnt(1) boundaries, raw
// lds_barrier, liveness pins from R21). Per-thread vmem ledger: 2h+1x loads
// then 1 store per phase -> boundary waits: A: t==0?vm0:vm1; B: t==STEPS?
// vm0:vm1 (no A-store at STEPS).
constexpr u64 TAG_MASK = 0x0001000100010001ull;
__device__ __forceinline__ u64 tag_of(int t) {
  return ((u64)(t & 1) | ((u64)((t >> 1) & 1) << 16)) * 0x0000000100000001ull;
}

__global__ void init_kernel(int* wsi) {
  int idx = blockIdx.x * blockDim.x + threadIdx.x;
  int stride = gridDim.x * blockDim.x;
  const int nws = (HB_OFF + BATCH * HDIM * 2) / 4;  // hbuf[0] = h_0 = 0 (tag 00)
  for (int i = idx; i < nws; i += stride) wsi[i] = 0;
  // hbuf[1] stays poison -> tag-invalid until written
}

static __device__ __forceinline__ f16x8 load16_llc(const _Float16* p) {
  f16x8 v;
  asm volatile("global_load_dwordx4 %0, %1, off sc0 sc1"
               : "=v"(v) : "v"((u64)p) : "memory");
  return v;
}
static __device__ __forceinline__ unsigned loadc_llc(const void* p) {
  unsigned v;   // 4B canary: in-band tag probe
  asm volatile("global_load_dword %0, %1, off sc0 sc1"
               : "=v"(v) : "v"((u64)p) : "memory");
  return v;
}
static __device__ __forceinline__ float loadx(const float* p) {
  float v;   // plain cached load via asm so compiler never drains our pipeline
  asm volatile("global_load_dword %0, %1, off"
               : "=v"(v) : "v"((u64)p) : "memory");
  return v;
}
// s_sleep needs a literal operand: 4-step constant backoff ladder.
static __device__ __forceinline__ void sleep_bk(int stage) {
  if (stage == 0)      __builtin_amdgcn_s_sleep(1);
  else if (stage == 1) __builtin_amdgcn_s_sleep(2);
  else if (stage == 2) __builtin_amdgcn_s_sleep(4);
  else                 __builtin_amdgcn_s_sleep(8);
}
// fenced waits (rule #18): checks gating on a wait must not hoist above it.
static __device__ __forceinline__ void wait_vm0_fenced() {
  asm volatile("s_waitcnt vmcnt(0)" ::: "memory");
  __builtin_amdgcn_sched_barrier(0);
}
static __device__ __forceinline__ void wait_vm1_fenced() {
  asm volatile("s_waitcnt vmcnt(1)" ::: "memory");
  __builtin_amdgcn_sched_barrier(0);
}
// raw barrier: LDS-drain + s_barrier, NO vmcnt drain (stores/loads in flight)
static __device__ __forceinline__ void lds_barrier() {
  asm volatile("s_waitcnt lgkmcnt(0)" ::: "memory");
  __builtin_amdgcn_s_barrier();
}

__global__ __launch_bounds__(512, 2) void lstm_persist(
    const float* __restrict__ x,
    const float* __restrict__ w_ih,
    const float* __restrict__ w_hh,
    const float* __restrict__ b_ih,
    const float* __restrict__ b_hh,
    const float* __restrict__ w_fc,
    const float* __restrict__ b_fc,
    float* __restrict__ out,          // [1024][48] fp32
    _Float16* __restrict__ hbuf)      // [2][1024][512] fp16 ping-pong, tagged
{
  const int bid  = blockIdx.x;        // 256 blocks: 32 clusters x 8 unit-slices
  const int gA   = bid >> 3;          // group A (0..31); B = gA+32
  const int ub   = bid & 7;
  const int tid  = threadIdx.x;       // 0..511
  const int wid  = tid >> 6;          // 0..7
  const int ws   = wid >> 2;          // waveset 0: gates i,f; 1: gates g,o
  const int wq   = wid & 3;           // wave-in-set -> 16-unit column slice
  const int lane = tid & 63;
  const int quad = lane >> 4;
  const int lcol = lane & 15;
  const int bA0  = gA * GB;
  const int bB0  = bA0 + NG / 2 * GB; // = bA0 + 512
  const int myu  = ub * UBU + wq * 16 + lcol;   // GEMM-layout unit
  const int cb   = tid >> 5;          // epilogue cell batch (0..15)
  const int cu   = (tid * 2) & 63;    // epilogue cell unit pair base (even)

  __shared__ __align__(16) _Float16 hsA[GB][520];    // 16.6 KB
  __shared__ __align__(16) _Float16 hsB[GB][520];    // 16.6 KB
  __shared__ __align__(16) _Float16 wz[520];         // fp16 w_fc + zero pad
  __shared__ float gl[4][GB][68];                    // 17.4 KB gate exchange (padded)
  __shared__ float xls[GB];                          // dec: fc(h) per batch
  __shared__ float outs[2][GB][PRED];                // 6 KB predictions

  wz[tid < 512 ? tid : 0] = (_Float16)w_fc[tid < 512 ? tid : 0];
  if (tid < 8) wz[512 + tid] = (_Float16)0.f;

  // ---- GEMM-layout weights: 2 gates per thread (halved vs R18) ----
  f16x8 wf2[2][16];
#pragma unroll
  for (int ntl = 0; ntl < 2; ++ntl) {
    const int j = (2 * ws + ntl) * HDIM + myu;
#pragma unroll
    for (int kc = 0; kc < 16; ++kc) {
      const float* s = w_hh + (size_t)j * HDIM + kc * 32 + quad * 8;
      f16x8 v;
#pragma unroll
      for (int i = 0; i < 8; ++i) v[i] = (_Float16)s[i];
      wf2[ntl][kc] = v;
    }
  }
  // ---- cell-layout weights for the epilogue (2 cells x 4 gates) ----
  float wihc[2][4], biasc[2][4];
#pragma unroll
  for (int e = 0; e < 2; ++e)
#pragma unroll
    for (int g = 0; g < 4; ++g) {
      const int j = g * HDIM + ub * UBU + cu + e;
      wihc[e][g]  = w_ih[j];
      biasc[e][g] = b_ih[j] + b_hh[j];
    }
  const float bfc = b_fc[0];

  float cstA2[2] = {0.f, 0.f}, cstB2[2] = {0.f, 0.f};
  f16x8 tA[2], tB[2];
  float xA, xB;

  // staging: 1024 16B-chunks, 512 threads -> 2 each (c = i*512+tid)
  auto issue2 = [&](f16x8* tr, const _Float16* base) {
#pragma unroll
    for (int i = 0; i < 2; ++i) {
      const int c = i * 512 + tid;
      tr[i] = load16_llc(base + (size_t)(c >> 6) * HDIM + (c & 63) * 8);
    }
  };
  auto validate2 = [&](f16x8* tr, const _Float16* base, u64 expect) {
    const unsigned exp32 = (unsigned)expect & 0x00010001u;
    unsigned stale = 0;
#pragma unroll
    for (int i = 0; i < 2; ++i) {
      u64x2 w2 = __builtin_bit_cast(u64x2, tr[i]);
      if (((w2[0] & TAG_MASK) != expect) || ((w2[1] & TAG_MASK) != expect))
        stale |= 1u << i;
    }
    int slp = 0;
    while (stale) {
      sleep_bk(slp);
      if (slp < 3) ++slp;
      unsigned cv[2];
#pragma unroll
      for (int i = 0; i < 2; ++i)
        if (stale & (1u << i)) {
          const int c = i * 512 + tid;
          cv[i] = loadc_llc(base + (size_t)(c >> 6) * HDIM + (c & 63) * 8);
        }
      wait_vm0_fenced();          // canary values readable only after this
      unsigned rdy = 0;
#pragma unroll
      for (int i = 0; i < 2; ++i)
        if ((stale & (1u << i)) && ((cv[i] & 0x00010001u) == exp32))
          rdy |= 1u << i;
      if (!rdy) continue;
#pragma unroll
      for (int i = 0; i < 2; ++i)
        if (rdy & (1u << i)) {
          const int c = i * 512 + tid;
          tr[i] = load16_llc(base + (size_t)(c >> 6) * HDIM + (c & 63) * 8);
        }
      wait_vm0_fenced();          // reloads readable only after this
#pragma unroll
      for (int i = 0; i < 2; ++i)
        if (rdy & (1u << i)) {
          u64x2 w2 = __builtin_bit_cast(u64x2, tr[i]);
          if (((w2[0] & TAG_MASK) == expect) && ((w2[1] & TAG_MASK) == expect))
            stale &= ~(1u << i);
        }
    }
  };
  auto stage2 = [&](f16x8* tr, _Float16 (*hsp)[520]) {
#pragma unroll
    for (int i = 0; i < 2; ++i) {
      const int c = i * 512 + tid;
      *reinterpret_cast<f16x8*>(&hsp[c >> 6][(c & 63) * 8]) = tr[i];
    }
  };
  auto gemm2 = [&](const _Float16 (*hsp)[520], f32x4* acc, f32x4& accF, bool dec) {
#pragma unroll
    for (int kc = 0; kc < 16; ++kc) {
      const f16x8 a = *reinterpret_cast<const f16x8*>(&hsp[lcol][kc * 32 + quad * 8]);
      acc[0] = __builtin_amdgcn_mfma_f32_16x16x32_f16(a, wf2[0][kc], acc[0], 0, 0, 0);
      acc[1] = __builtin_amdgcn_mfma_f32_16x16x32_f16(a, wf2[1][kc], acc[1], 0, 0, 0);
      if (dec && ws == 0) {   // fc computed redundantly per ws0 wave (full K)
        const f16x8 wv = *reinterpret_cast<const f16x8*>(
            &wz[(lcol == 0) ? (kc * 32 + quad * 8) : 512]);
        accF = __builtin_amdgcn_mfma_f32_16x16x32_f16(a, wv, accF, 0, 0, 0);
      }
    }
  };
  // gates -> LDS -> barrier -> per-cell epilogue (2 cells/thread) -> h store
  auto phase_epi = [&](f32x4* acc, f32x4& accF, float xreg, float* cstv,
                       int bX0, int gidx, int t, _Float16* hnxt, bool dec) {
#pragma unroll
    for (int ntl = 0; ntl < 2; ++ntl)
#pragma unroll
      for (int r = 0; r < 4; ++r)
        gl[2 * ws + ntl][quad * 4 + r][wq * 16 + lcol] = acc[ntl][r];
    if (dec && wid == 0 && lcol == 0) {   // lanes 0,16,32,48 of wave 0
#pragma unroll
      for (int r = 0; r < 4; ++r) xls[quad * 4 + r] = accF[r] + bfc;
    }
    lds_barrier();
    if (dec && ub == 0 && (tid & 31) == 0)
      outs[gidx][cb][t - TENC] = xls[cb];
    const float xt = dec ? xls[cb] : xreg;
    if (t < STEPS) {
      const unsigned tag32 = (unsigned)tag_of(t + 1);
      unsigned v32 = 0;
#pragma unroll
      for (int e = 0; e < 2; ++e) {
        const int u = cu + e;
        const float gi = gl[0][cb][u] + xt * wihc[e][0] + biasc[e][0];
        const float gf = gl[1][cb][u] + xt * wihc[e][1] + biasc[e][1];
        const float gg = gl[2][cb][u] + xt * wihc[e][2] + biasc[e][2];
        const float go = gl[3][cb][u] + xt * wihc[e][3] + biasc[e][3];
        const float si = 1.f / (1.f + __expf(-gi));
        const float sf = 1.f / (1.f + __expf(-gf));
        const float so = 1.f / (1.f + __expf(-go));
        const float tg = 1.f - 2.f / (1.f + __expf(2.f * gg));
        const float cn = sf * cstv[e] + si * tg;
        cstv[e] = cn;
        const float tc = 1.f - 2.f / (1.f + __expf(2.f * cn));
        const unsigned short hb =
            __builtin_bit_cast(unsigned short, (_Float16)(so * tc));
        v32 |= ((unsigned)hb) << (16 * e);
      }
      v32 = (v32 & ~0x00010001u) | tag32;
      unsigned* dst = (unsigned*)(hnxt + (size_t)(bX0 + cb) * HDIM
                                  + ub * UBU + cu);
      __hip_atomic_store(dst, v32, __ATOMIC_RELAXED, __HIP_MEMORY_SCOPE_AGENT);
    }
  };

  lds_barrier();   // wz visible

  // ---- prologue: A(0) data in flight (2h + 1x per thread) ----
  issue2(tA, hbuf + (size_t)bA0 * HDIM);
  xA = loadx(x + (size_t)(bA0 + cb) * TENC + 0);

  for (int t = 0; t <= STEPS; ++t) {
    const _Float16* hcur = hbuf + (size_t)(t & 1) * BATCH * HDIM;
    _Float16*       hnxt = hbuf + (size_t)((t + 1) & 1) * BATCH * HDIM;
    const u64 expect = tag_of(t);
    const bool dec = (t >= TENC);

    // ================= phase A =================
    // per-thread outstanding: tA(2), xA(1), [storeB(t-1)] -> vmcnt(1)
    if (t == 0) wait_vm0_fenced();
    else        wait_vm1_fenced();
    asm volatile("" :: "v"(xA));   // liveness pin (R21-proven)
    validate2(tA, hcur + (size_t)bA0 * HDIM, expect);
    stage2(tA, hsA);
    lds_barrier();
    issue2(tB, hcur + (size_t)bB0 * HDIM);             // B(t) flies during A
    xB = loadx(x + (size_t)(bB0 + cb) * TENC + (t < TENC ? t : TENC - 1));

    f32x4 accA[2], accFA;
    accA[0] = (f32x4){0.f, 0.f, 0.f, 0.f};
    accA[1] = (f32x4){0.f, 0.f, 0.f, 0.f};
    accFA = (f32x4){0.f, 0.f, 0.f, 0.f};
    gemm2(hsA, accA, accFA, dec);
    phase_epi(accA, accFA, xA, cstA2, bA0, 0, t, hnxt, dec);

    // ================= phase B =================
    // outstanding: tB(2), xB(1), [storeA] -> vmcnt(1); t==STEPS: no storeA
    if (t == STEPS) wait_vm0_fenced();
    else            wait_vm1_fenced();
    asm volatile("" :: "v"(xB));   // liveness pin
    validate2(tB, hcur + (size_t)bB0 * HDIM, expect);
    stage2(tB, hsB);
    lds_barrier();
    if (t < STEPS) {
      issue2(tA, hnxt + (size_t)bA0 * HDIM);           // A(t+1) flies during B
      xA = loadx(x + (size_t)(bA0 + cb) * TENC
                 + (t + 1 < TENC ? t + 1 : TENC - 1));
    }

    f32x4 accB[2], accFB;
    accB[0] = (f32x4){0.f, 0.f, 0.f, 0.f};
    accB[1] = (f32x4){0.f, 0.f, 0.f, 0.f};
    accFB = (f32x4){0.f, 0.f, 0.f, 0.f};
    gemm2(hsB, accB, accFB, dec);
    phase_epi(accB, accFB, xB, cstB2, bB0, 1, t, hnxt, dec);
  }

  // flush buffered predictions
  lds_barrier();
  if (ub == 0) {
    for (int k = tid; k < 2 * GB * PRED; k += 512) {
      const int g  = k / (GB * PRED);
      const int rm = k % (GB * PRED);
      out[(size_t)((g ? bB0 : bA0) + rm / PRED) * PRED + (rm % PRED)] =
          outs[g][rm / PRED][rm % PRED];
    }
  }
}

extern "C" void kernel_launch(void* const* d_in, const int* in_sizes, int n_in,
                              void* d_out, int out_size, void* d_ws, size_t ws_size,
                              hipStream_t stream) {
  const float* x    = (const float*)d_in[0];
  const float* w_ih = (const float*)d_in[1];
  const float* w_hh = (const float*)d_in[2];
  const float* b_ih = (const float*)d_in[3];
  const float* b_hh = (const float*)d_in[4];
  const float* w_fc = (const float*)d_in[5];
  const float* b_fc = (const float*)d_in[6];
  float* out = (float*)d_out;
  _Float16* hbuf = (_Float16*)((char*)d_ws + HB_OFF);

  hipLaunchKernelGGL(init_kernel, dim3(256), dim3(256), 0, stream, (int*)d_ws);
  hipLaunchKernelGGL(lstm_persist, dim3(256), dim3(512), 0, stream,
                     x, w_ih, w_hh, b_ih, b_hh, w_fc, b_fc, out, hbuf);
}